// Round 8
// baseline (213.977 us; speedup 1.0000x reference)
//
#include <hip/hip_runtime.h>
#include <hip/hip_fp16.h>
#include <math.h>

#define N_DRUG 20000
#define N_PROT 30000
#define NN (N_DRUG + N_PROT)
#define F_DRUG 128
#define F_PROT 256
#define H 64
#define NE 1600000
#define NL 200000

#define NB_PROJD ((N_DRUG + 127) / 128)          // 157 (128 rows/block)
#define NB_PROJP ((N_PROT + 127) / 128)          // 235
#define NB_CONV  ((NN + 255) / 256)              // 196 (256 rows/block)
#define NB_ROW4  ((NN + 3) / 4)                  // 12500 (4 rows/block, warp per row)
#define NBK1 256                                  // partition blocks
#define CH   ((NE + NBK1 - 1) / NBK1)            // 6250 edges/block
#define NB_BKT ((NN + 255) / 256)                // 196 buckets

typedef _Float16 h8 __attribute__((ext_vector_type(8)));
typedef _Float16 h4 __attribute__((ext_vector_type(4)));
typedef float f32x4 __attribute__((ext_vector_type(4)));

#define MFMA16(a, b, c) __builtin_amdgcn_mfma_f32_16x16x32_f16((a), (b), (c), 0, 0, 0)

// ---------------- weight prep: transpose + fp16 ([c][k] layout) ----------------
__global__ __launch_bounds__(256) void k_wprep(
    const float* __restrict__ Wd, const float* __restrict__ Wp,
    const float* __restrict__ cw,
    _Float16* __restrict__ wdt, _Float16* __restrict__ wpt,
    _Float16* __restrict__ cwt) {
    int i = blockIdx.x * 256 + threadIdx.x;
    if (i < 64 * F_DRUG) {
        int c = i / F_DRUG, k = i % F_DRUG;
        wdt[i] = (_Float16)Wd[k * H + c];
    }
    if (i < 64 * F_PROT) {
        int c = i / F_PROT, k = i % F_PROT;
        wpt[i] = (_Float16)Wp[k * H + c];
    }
    if (i < 3 * 64 * 64) {
        int l = i >> 12, r = i & 4095;
        int c = r >> 6, k = r & 63;
        cwt[i] = (_Float16)cw[(l << 12) + k * H + c];
    }
}

// ---------------- zero-LDS MFMA projection: out = relu(X@W + b) as fp16 ----------------
template <int F>
__device__ __forceinline__ void proj_direct(
    const float* __restrict__ X, const _Float16* __restrict__ Wt,
    const float* __restrict__ bias, __half* __restrict__ out,
    int rows, int row_off, int bid) {
    int l = threadIdx.x & 63, wvi = threadIdx.x >> 6;
    int lr = l & 15, lq = l >> 4;
    int r0 = bid * 128 + wvi * 32;
    f32x4 acc[2][4];
    #pragma unroll
    for (int rt = 0; rt < 2; ++rt)
        #pragma unroll
        for (int n = 0; n < 4; ++n) acc[rt][n] = (f32x4){0.f, 0.f, 0.f, 0.f};

    for (int k0 = 0; k0 < F; k0 += 64) {
        h8 af[4][2];
        #pragma unroll
        for (int n = 0; n < 4; ++n)
            #pragma unroll
            for (int kk = 0; kk < 2; ++kk)
                af[n][kk] = *(const h8*)&Wt[(size_t)(n * 16 + lr) * F + k0 + kk * 32 + lq * 8];
        #pragma unroll
        for (int rt = 0; rt < 2; ++rt) {
            int r = r0 + rt * 16 + lr;
            int rc = (r < rows) ? r : (rows - 1);
            h8 bf[2];
            #pragma unroll
            for (int kk = 0; kk < 2; ++kk) {
                const float* xp = X + (size_t)rc * F + k0 + kk * 32 + lq * 8;
                float4 a = *(const float4*)xp;
                float4 b = *(const float4*)(xp + 4);
                h8 t;
                t[0] = (_Float16)a.x; t[1] = (_Float16)a.y;
                t[2] = (_Float16)a.z; t[3] = (_Float16)a.w;
                t[4] = (_Float16)b.x; t[5] = (_Float16)b.y;
                t[6] = (_Float16)b.z; t[7] = (_Float16)b.w;
                bf[kk] = t;
            }
            #pragma unroll
            for (int n = 0; n < 4; ++n) {
                acc[rt][n] = MFMA16(af[n][0], bf[0], acc[rt][n]);
                acc[rt][n] = MFMA16(af[n][1], bf[1], acc[rt][n]);
            }
        }
    }
    #pragma unroll
    for (int rt = 0; rt < 2; ++rt) {
        int r = r0 + rt * 16 + lr;
        if (r < rows) {
            #pragma unroll
            for (int n = 0; n < 4; ++n) {
                int c = n * 16 + lq * 4;
                float4 bv = *(const float4*)&bias[c];
                h4 hv;
                hv[0] = (_Float16)fmaxf(acc[rt][n][0] + bv.x, 0.f);
                hv[1] = (_Float16)fmaxf(acc[rt][n][1] + bv.y, 0.f);
                hv[2] = (_Float16)fmaxf(acc[rt][n][2] + bv.z, 0.f);
                hv[3] = (_Float16)fmaxf(acc[rt][n][3] + bv.w, 0.f);
                *(h4*)((_Float16*)out + (size_t)(row_off + r) * H + c) = hv;
            }
        }
    }
}

// ---------------- zero-LDS MFMA conv: xw = x @ Wl (fp16 in/out, fp32 acc) ----------------
__device__ __forceinline__ void conv_direct(
    const __half* __restrict__ xin, const _Float16* __restrict__ Wt,
    __half* __restrict__ xout, int bid) {
    int l = threadIdx.x & 63, wvi = threadIdx.x >> 6;
    int lr = l & 15, lq = l >> 4;
    const _Float16* xh = (const _Float16*)xin;
    h8 af[4][2];
    #pragma unroll
    for (int n = 0; n < 4; ++n)
        #pragma unroll
        for (int kk = 0; kk < 2; ++kk)
            af[n][kk] = *(const h8*)&Wt[(size_t)(n * 16 + lr) * 64 + kk * 32 + lq * 8];
    int r0 = bid * 256 + wvi * 64;
    #pragma unroll
    for (int rt = 0; rt < 4; ++rt) {
        int r = r0 + rt * 16 + lr;
        int rc = (r < NN) ? r : (NN - 1);
        h8 bf0 = *(const h8*)&xh[(size_t)rc * H + lq * 8];
        h8 bf1 = *(const h8*)&xh[(size_t)rc * H + 32 + lq * 8];
        f32x4 a[4];
        #pragma unroll
        for (int n = 0; n < 4; ++n) {
            a[n] = (f32x4){0.f, 0.f, 0.f, 0.f};
            a[n] = MFMA16(af[n][0], bf0, a[n]);
            a[n] = MFMA16(af[n][1], bf1, a[n]);
        }
        if (r < NN) {
            #pragma unroll
            for (int n = 0; n < 4; ++n) {
                int c = n * 16 + lq * 4;
                h4 hv;
                hv[0] = (_Float16)a[n][0]; hv[1] = (_Float16)a[n][1];
                hv[2] = (_Float16)a[n][2]; hv[3] = (_Float16)a[n][3];
                *(h4*)((_Float16*)xout + (size_t)r * H + c) = hv;
            }
        }
    }
}

// ---------------- fused front: proj_drug || proj_prot || coarse bucket hist ----------------
__global__ __launch_bounds__(256) void k_front(
    const float* __restrict__ xd, const _Float16* __restrict__ wdt, const float* __restrict__ bd,
    const float* __restrict__ xp, const _Float16* __restrict__ wpt, const float* __restrict__ bp,
    const int* __restrict__ ei, unsigned* __restrict__ bhist, __half* __restrict__ xbuf) {
    __shared__ unsigned lh[256];
    int bid = blockIdx.x;
    if (bid < NB_PROJD) {
        proj_direct<F_DRUG>(xd, wdt, bd, xbuf, N_DRUG, 0, bid);
    } else if (bid < NB_PROJD + NB_PROJP) {
        proj_direct<F_PROT>(xp, wpt, bp, xbuf, N_PROT, N_DRUG, bid - NB_PROJD);
    } else {
        int blk = bid - NB_PROJD - NB_PROJP;
        int t = threadIdx.x;
        lh[t] = 0;
        __syncthreads();
        int eb = blk * CH, ee = min(NE, eb + CH);
        for (int e = eb + t; e < ee; e += 256)
            atomicAdd(&lh[((unsigned)ei[NE + e]) >> 8], 1u);
        __syncthreads();
        bhist[(size_t)t * NBK1 + blk] = lh[t];
    }
}

// ---------------- scan step A: per-bucket row sums ----------------
__global__ __launch_bounds__(256) void kA(const unsigned* __restrict__ bhist,
                                          unsigned* __restrict__ rsum) {
    __shared__ unsigned s[256];
    int j = blockIdx.x, t = threadIdx.x;
    s[t] = bhist[(size_t)j * NBK1 + t];
    __syncthreads();
    for (int off = 128; off; off >>= 1) {
        if (t < off) s[t] += s[t + off];
        __syncthreads();
    }
    if (t == 0) rsum[j] = s[0];
}

// ---------------- scan step B: exclusive scan of bucket totals ----------------
__global__ __launch_bounds__(256) void kB(const unsigned* __restrict__ rsum,
                                          unsigned* __restrict__ rbase) {
    __shared__ unsigned s[256];
    int t = threadIdx.x;
    unsigned c = rsum[t];
    s[t] = c;
    __syncthreads();
    for (int off = 1; off < 256; off <<= 1) {
        unsigned v = s[t]; unsigned u = (t >= off) ? s[t - off] : 0;
        __syncthreads(); s[t] = v + u; __syncthreads();
    }
    rbase[t] = s[t] - c;
    if (t == 255) rbase[256] = s[255];
}

// ---------------- scan step C: per-bucket row exclusive scan + offset ----------------
__global__ __launch_bounds__(256) void kC(unsigned* __restrict__ bhist,
                                          const unsigned* __restrict__ rbase) {
    __shared__ unsigned s[256];
    int j = blockIdx.x, t = threadIdx.x;
    unsigned c = bhist[(size_t)j * NBK1 + t];
    s[t] = c;
    __syncthreads();
    for (int off = 1; off < 256; off <<= 1) {
        unsigned v = s[t]; unsigned u = (t >= off) ? s[t - off] : 0;
        __syncthreads(); s[t] = v + u; __syncthreads();
    }
    bhist[(size_t)j * NBK1 + t] = rbase[j] + s[t] - c;
}

// ---------------- bucket partition-scatter (LDS cursors) ----------------
__global__ __launch_bounds__(256) void k_part(
    const int* __restrict__ ei, const unsigned* __restrict__ base,
    unsigned* __restrict__ tmp) {
    __shared__ unsigned lcur[256];
    int bid = blockIdx.x;
    int t = threadIdx.x;
    lcur[t] = base[(size_t)t * NBK1 + bid];
    __syncthreads();
    int eb = bid * CH, ee = min(NE, eb + CH);
    for (int e = eb + t; e < ee; e += 256) {
        unsigned s = (unsigned)ei[e];
        unsigned d = (unsigned)ei[NE + e];
        unsigned pos = atomicAdd(&lcur[d >> 8], 1u);
        tmp[pos] = ((d & 255u) << 16) | s;
    }
}

// ---------------- per-bucket CSR finalize: rp, dis, csr(u16) ----------------
__global__ __launch_bounds__(256) void k_csr(
    const unsigned* __restrict__ tmp, const unsigned* __restrict__ rbase,
    int* __restrict__ rp, float* __restrict__ dis,
    unsigned short* __restrict__ csr) {
    __shared__ unsigned lbin[256], lofs[256], lcur[256];
    int b = blockIdx.x, t = threadIdx.x;
    unsigned nb0 = rbase[b], nb1 = rbase[b + 1];
    lbin[t] = 0;
    __syncthreads();
    for (unsigned i = nb0 + t; i < nb1; i += 256)
        atomicAdd(&lbin[tmp[i] >> 16], 1u);
    __syncthreads();
    unsigned c = lbin[t];
    lofs[t] = c;
    __syncthreads();
    for (int off = 1; off < 256; off <<= 1) {
        unsigned v = lofs[t]; unsigned u = (t >= off) ? lofs[t - off] : 0;
        __syncthreads(); lofs[t] = v + u; __syncthreads();
    }
    unsigned r = nb0 + lofs[t] - c;
    int node = b * 256 + t;
    if (node < NN) {
        rp[node] = (int)r;
        dis[node] = rsqrtf((float)c + 1.0f);
    }
    lcur[t] = r;
    __syncthreads();
    for (unsigned i = nb0 + t; i < nb1; i += 256) {
        unsigned rec = tmp[i];
        unsigned pos = atomicAdd(&lcur[rec >> 16], 1u);
        csr[pos] = (unsigned short)(rec & 0xffffu);
    }
    if (b == 0 && t == 0) rp[NN] = NE;
}

// ---------------- fused: conv layer 0 || weight-pack (src | f16(dis_s*dis_d) << 16) ----------------
__global__ __launch_bounds__(256) void k_pc(
    const int* __restrict__ rp, const unsigned short* __restrict__ csr,
    const float* __restrict__ dis, unsigned* __restrict__ pack,
    const __half* __restrict__ xbuf, const _Float16* __restrict__ cwt,
    __half* __restrict__ xwh) {
    int bid = blockIdx.x;
    if (bid < NB_CONV) {
        conv_direct(xbuf, cwt, xwh, bid);
    } else {
        int d = (bid - NB_CONV) * 4 + (threadIdx.x >> 6);
        if (d >= NN) return;
        int lane = threadIdx.x & 63;
        int beg = rp[d], end = rp[d + 1];
        float dd = dis[d];
        for (int i = beg + lane; i < end; i += 64) {
            int s = csr[i];
            float w = dis[s] * dd;
            pack[i] = (unsigned)s |
                      ((unsigned)__half_as_ushort(__float2half(w)) << 16);
        }
    }
}

// ---------------- standalone conv (layers 1,2) ----------------
__global__ __launch_bounds__(256) void k_conv(
    const __half* __restrict__ X, const _Float16* __restrict__ Wt, __half* __restrict__ out) {
    conv_direct(X, Wt, out, blockIdx.x);
}

// ---------------- SpMM quarter-wave, packed (src,w) edges ----------------
// lane: q = lane>>4 (edge slot), g = lane&15 (features 4g..4g+3).
template <bool LAST>
__global__ __launch_bounds__(256) void k_spmm(
    const int* __restrict__ rp, const unsigned* __restrict__ pack,
    const float* __restrict__ dis, const __half* __restrict__ xw,
    const float* __restrict__ bias, __half* __restrict__ xout,
    const float* __restrict__ lw, const float* __restrict__ lb,
    float* __restrict__ y) {
    int lane = threadIdx.x & 63;
    int d = blockIdx.x * 4 + (threadIdx.x >> 6);
    if (d >= NN) return;
    int q = lane >> 4, g = lane & 15;
    int beg = rp[d], end = rp[d + 1];
    const _Float16* xh = (const _Float16*)xw;
    float ax = 0.f, ay = 0.f, az = 0.f, aw = 0.f;

    int n = end - beg; if (n > 64) n = 64;
    unsigned rv = 0;
    if (lane < n) rv = pack[beg + lane];
    for (int b0 = beg; b0 < end; ) {
        int nb = b0 + 64;
        int n2 = end - nb; if (n2 > 64) n2 = 64;
        unsigned rv2 = 0;
        if (n2 > 0 && lane < n2) rv2 = pack[nb + lane];
        int nsteps = (n + 3) >> 2;
        #pragma unroll 4
        for (int jj = 0; jj < nsteps; ++jj) {
            unsigned r = __shfl(rv, jj * 4 + q);   // w==0 masks idx >= n
            int s = (int)(r & 0xffffu);
            float w = __half2float(__ushort_as_half((unsigned short)(r >> 16)));
            h4 xv = *(const h4*)&xh[((unsigned)s << 6) + (g << 2)];
            ax += w * (float)xv[0];
            ay += w * (float)xv[1];
            az += w * (float)xv[2];
            aw += w * (float)xv[3];
        }
        b0 = nb; n = n2; rv = rv2;
    }
    // reduce across the 4 quarters
    ax += __shfl_xor(ax, 16); ay += __shfl_xor(ay, 16);
    az += __shfl_xor(az, 16); aw += __shfl_xor(aw, 16);
    ax += __shfl_xor(ax, 32); ay += __shfl_xor(ay, 32);
    az += __shfl_xor(az, 32); aw += __shfl_xor(aw, 32);

    // epilogue: self term + bias + relu (edge weights are pre-multiplied)
    float dd = dis[d];
    float sn = dd * dd;
    h4 xs = *(const h4*)&xh[((unsigned)d << 6) + (g << 2)];
    float4 bv = *(const float4*)&bias[g << 2];
    float vx = fmaxf(ax + sn * (float)xs[0] + bv.x, 0.f);
    float vy = fmaxf(ay + sn * (float)xs[1] + bv.y, 0.f);
    float vz = fmaxf(az + sn * (float)xs[2] + bv.z, 0.f);
    float vw = fmaxf(aw + sn * (float)xs[3] + bv.w, 0.f);
    if (LAST) {
        float4 lv = *(const float4*)&lw[g << 2];
        float t = vx * lv.x + vy * lv.y + vz * lv.z + vw * lv.w;
        #pragma unroll
        for (int off = 8; off; off >>= 1) t += __shfl_xor(t, off);
        if (lane == 0) y[d] = t + lb[0];
    } else if (q == 0) {
        h4 hv;
        hv[0] = (_Float16)vx; hv[1] = (_Float16)vy;
        hv[2] = (_Float16)vz; hv[3] = (_Float16)vw;
        *(h4*)((_Float16*)xout + ((size_t)d << 6) + (g << 2)) = hv;
    }
}

// ---------------- edge scoring: sigmoid(y[src]*y[dst]) ----------------
__global__ void k_out(const float* __restrict__ y, const int* __restrict__ ls,
                      const int* __restrict__ ld, float* __restrict__ out) {
    int e = blockIdx.x * blockDim.x + threadIdx.x;
    if (e < NL) {
        float z = y[ls[e]] * y[ld[e]];
        out[e] = 1.f / (1.f + __expf(-z));
    }
}

static inline size_t up256(size_t x) { return (x + 255) & ~(size_t)255; }

extern "C" void kernel_launch(void* const* d_in, const int* in_sizes, int n_in,
                              void* d_out, int out_size, void* d_ws, size_t ws_size,
                              hipStream_t stream) {
    const float* x_drug = (const float*)d_in[0];
    const float* x_prot = (const float*)d_in[1];
    const float* W_drug = (const float*)d_in[2];
    const float* b_drug = (const float*)d_in[3];
    const float* W_prot = (const float*)d_in[4];
    const float* b_prot = (const float*)d_in[5];
    const float* conv_W = (const float*)d_in[6];
    const float* conv_b = (const float*)d_in[7];
    const float* lin_W  = (const float*)d_in[8];
    const float* lin_b  = (const float*)d_in[9];
    const int*   ei     = (const int*)d_in[10];
    const int*   lsrc   = (const int*)d_in[11];
    const int*   ldst   = (const int*)d_in[12];
    float* out = (float*)d_out;

    char* w = (char*)d_ws;
    size_t off = 0;
    unsigned* bhist = (unsigned*)(w + off); off = up256(off + (size_t)256 * NBK1 * 4);
    unsigned* rsum  = (unsigned*)(w + off); off = up256(off + 256 * 4);
    unsigned* rbase = (unsigned*)(w + off); off = up256(off + 257 * 4);
    unsigned* tmp   = (unsigned*)(w + off); off = up256(off + (size_t)NE * 4);
    unsigned short* csr = (unsigned short*)(w + off); off = up256(off + (size_t)NE * 2);
    unsigned* pack  = (unsigned*)(w + off); off = up256(off + (size_t)NE * 4);
    int*    rp   = (int*)(w + off);    off = up256(off + (size_t)(NN + 1) * 4);
    float*  dis  = (float*)(w + off);  off = up256(off + (size_t)NN * 4);
    __half* xbuf = (__half*)(w + off); off = up256(off + (size_t)NN * H * 2);
    __half* xwh  = (__half*)(w + off); off = up256(off + (size_t)NN * H * 2);
    float*  y    = (float*)(w + off);  off = up256(off + (size_t)NN * 4);
    _Float16* wdt = (_Float16*)(w + off); off = up256(off + (size_t)64 * F_DRUG * 2);
    _Float16* wpt = (_Float16*)(w + off); off = up256(off + (size_t)64 * F_PROT * 2);
    _Float16* cwt = (_Float16*)(w + off); off = up256(off + (size_t)3 * 64 * 64 * 2);

    k_wprep<<<64, 256, 0, stream>>>(W_drug, W_prot, conv_W, wdt, wpt, cwt);

    // proj_drug || proj_prot || coarse hist
    k_front<<<NB_PROJD + NB_PROJP + NBK1, 256, 0, stream>>>(
        x_drug, wdt, b_drug, x_prot, wpt, b_prot, ei, bhist, xbuf);

    kA<<<256, 256, 0, stream>>>(bhist, rsum);
    kB<<<1, 256, 0, stream>>>(rsum, rbase);
    kC<<<256, 256, 0, stream>>>(bhist, rbase);

    // bucket partition-scatter
    k_part<<<NBK1, 256, 0, stream>>>(ei, bhist, tmp);

    // per-bucket CSR finalize (rp, dis, u16 src)
    k_csr<<<NB_BKT, 256, 0, stream>>>(tmp, rbase, rp, dis, csr);

    // conv layer 0 || edge weight pack
    k_pc<<<NB_CONV + NB_ROW4, 256, 0, stream>>>(rp, csr, dis, pack, xbuf, cwt, xwh);

    // layer 0
    k_spmm<false><<<NB_ROW4, 256, 0, stream>>>(
        rp, pack, dis, xwh, conv_b, xbuf, nullptr, nullptr, nullptr);
    // layer 1
    k_conv<<<NB_CONV, 256, 0, stream>>>(xbuf, cwt + 4096, xwh);
    k_spmm<false><<<NB_ROW4, 256, 0, stream>>>(
        rp, pack, dis, xwh, conv_b + H, xbuf, nullptr, nullptr, nullptr);
    // layer 2 (fused y epilogue)
    k_conv<<<NB_CONV, 256, 0, stream>>>(xbuf, cwt + 8192, xwh);
    k_spmm<true><<<NB_ROW4, 256, 0, stream>>>(
        rp, pack, dis, xwh, conv_b + 2 * H, nullptr, lin_W, lin_b, y);

    k_out<<<(NL + 255) / 256, 256, 0, stream>>>(y, lsrc, ldst, out);
}

// Round 9
// 206.207 us; speedup vs baseline: 1.0377x; 1.0377x over previous
//
#include <hip/hip_runtime.h>
#include <hip/hip_fp16.h>
#include <math.h>

#define N_DRUG 20000
#define N_PROT 30000
#define NN (N_DRUG + N_PROT)
#define F_DRUG 128
#define F_PROT 256
#define H 64
#define NE 1600000
#define NL 200000

#define NB_PROJD ((N_DRUG + 127) / 128)          // 157 (128 rows/block)
#define NB_PROJP ((N_PROT + 127) / 128)          // 235
#define NB_CONV  ((NN + 255) / 256)              // 196 (256 rows/block)
#define NB_ROW4  ((NN + 3) / 4)                  // 12500 (4 rows/block, warp per row)
#define NBK1 256                                  // partition chunks
#define CH   ((NE + NBK1 - 1) / NBK1)            // 6250 edges/chunk
#define NB_BKT ((NN + 255) / 256)                // 196 buckets

typedef _Float16 h8 __attribute__((ext_vector_type(8)));
typedef _Float16 h4 __attribute__((ext_vector_type(4)));
typedef float f32x4 __attribute__((ext_vector_type(4)));

#define MFMA16(a, b, c) __builtin_amdgcn_mfma_f32_16x16x32_f16((a), (b), (c), 0, 0, 0)

// ---------------- weight prep: transpose + fp16 ([c][k] layout) ----------------
__global__ __launch_bounds__(256) void k_wprep(
    const float* __restrict__ Wd, const float* __restrict__ Wp,
    const float* __restrict__ cw,
    _Float16* __restrict__ wdt, _Float16* __restrict__ wpt,
    _Float16* __restrict__ cwt) {
    int i = blockIdx.x * 256 + threadIdx.x;
    if (i < 64 * F_DRUG) {
        int c = i / F_DRUG, k = i % F_DRUG;
        wdt[i] = (_Float16)Wd[k * H + c];
    }
    if (i < 64 * F_PROT) {
        int c = i / F_PROT, k = i % F_PROT;
        wpt[i] = (_Float16)Wp[k * H + c];
    }
    if (i < 3 * 64 * 64) {
        int l = i >> 12, r = i & 4095;
        int c = r >> 6, k = r & 63;
        cwt[i] = (_Float16)cw[(l << 12) + k * H + c];
    }
}

// ---------------- zero-LDS MFMA projection: out = relu(X@W + b) as fp16 ----------------
template <int F>
__device__ __forceinline__ void proj_direct(
    const float* __restrict__ X, const _Float16* __restrict__ Wt,
    const float* __restrict__ bias, __half* __restrict__ out,
    int rows, int row_off, int bid) {
    int l = threadIdx.x & 63, wvi = threadIdx.x >> 6;
    int lr = l & 15, lq = l >> 4;
    int r0 = bid * 128 + wvi * 32;
    f32x4 acc[2][4];
    #pragma unroll
    for (int rt = 0; rt < 2; ++rt)
        #pragma unroll
        for (int n = 0; n < 4; ++n) acc[rt][n] = (f32x4){0.f, 0.f, 0.f, 0.f};

    for (int k0 = 0; k0 < F; k0 += 64) {
        h8 af[4][2];
        #pragma unroll
        for (int n = 0; n < 4; ++n)
            #pragma unroll
            for (int kk = 0; kk < 2; ++kk)
                af[n][kk] = *(const h8*)&Wt[(size_t)(n * 16 + lr) * F + k0 + kk * 32 + lq * 8];
        #pragma unroll
        for (int rt = 0; rt < 2; ++rt) {
            int r = r0 + rt * 16 + lr;
            int rc = (r < rows) ? r : (rows - 1);
            h8 bf[2];
            #pragma unroll
            for (int kk = 0; kk < 2; ++kk) {
                const float* xp = X + (size_t)rc * F + k0 + kk * 32 + lq * 8;
                float4 a = *(const float4*)xp;
                float4 b = *(const float4*)(xp + 4);
                h8 t;
                t[0] = (_Float16)a.x; t[1] = (_Float16)a.y;
                t[2] = (_Float16)a.z; t[3] = (_Float16)a.w;
                t[4] = (_Float16)b.x; t[5] = (_Float16)b.y;
                t[6] = (_Float16)b.z; t[7] = (_Float16)b.w;
                bf[kk] = t;
            }
            #pragma unroll
            for (int n = 0; n < 4; ++n) {
                acc[rt][n] = MFMA16(af[n][0], bf[0], acc[rt][n]);
                acc[rt][n] = MFMA16(af[n][1], bf[1], acc[rt][n]);
            }
        }
    }
    #pragma unroll
    for (int rt = 0; rt < 2; ++rt) {
        int r = r0 + rt * 16 + lr;
        if (r < rows) {
            #pragma unroll
            for (int n = 0; n < 4; ++n) {
                int c = n * 16 + lq * 4;
                float4 bv = *(const float4*)&bias[c];
                h4 hv;
                hv[0] = (_Float16)fmaxf(acc[rt][n][0] + bv.x, 0.f);
                hv[1] = (_Float16)fmaxf(acc[rt][n][1] + bv.y, 0.f);
                hv[2] = (_Float16)fmaxf(acc[rt][n][2] + bv.z, 0.f);
                hv[3] = (_Float16)fmaxf(acc[rt][n][3] + bv.w, 0.f);
                *(h4*)((_Float16*)out + (size_t)(row_off + r) * H + c) = hv;
            }
        }
    }
}

// ---------------- zero-LDS MFMA conv: xw = x @ Wl (fp16 in/out, fp32 acc) ----------------
__device__ __forceinline__ void conv_direct(
    const __half* __restrict__ xin, const _Float16* __restrict__ Wt,
    __half* __restrict__ xout, int bid) {
    int l = threadIdx.x & 63, wvi = threadIdx.x >> 6;
    int lr = l & 15, lq = l >> 4;
    const _Float16* xh = (const _Float16*)xin;
    h8 af[4][2];
    #pragma unroll
    for (int n = 0; n < 4; ++n)
        #pragma unroll
        for (int kk = 0; kk < 2; ++kk)
            af[n][kk] = *(const h8*)&Wt[(size_t)(n * 16 + lr) * 64 + kk * 32 + lq * 8];
    int r0 = bid * 256 + wvi * 64;
    #pragma unroll
    for (int rt = 0; rt < 4; ++rt) {
        int r = r0 + rt * 16 + lr;
        int rc = (r < NN) ? r : (NN - 1);
        h8 bf0 = *(const h8*)&xh[(size_t)rc * H + lq * 8];
        h8 bf1 = *(const h8*)&xh[(size_t)rc * H + 32 + lq * 8];
        f32x4 a[4];
        #pragma unroll
        for (int n = 0; n < 4; ++n) {
            a[n] = (f32x4){0.f, 0.f, 0.f, 0.f};
            a[n] = MFMA16(af[n][0], bf0, a[n]);
            a[n] = MFMA16(af[n][1], bf1, a[n]);
        }
        if (r < NN) {
            #pragma unroll
            for (int n = 0; n < 4; ++n) {
                int c = n * 16 + lq * 4;
                h4 hv;
                hv[0] = (_Float16)a[n][0]; hv[1] = (_Float16)a[n][1];
                hv[2] = (_Float16)a[n][2]; hv[3] = (_Float16)a[n][3];
                *(h4*)((_Float16*)xout + (size_t)r * H + c) = hv;
            }
        }
    }
}

// ---------------- fused front: proj_drug || proj_prot || coarse bucket hist ----------------
__global__ __launch_bounds__(256) void k_front(
    const float* __restrict__ xd, const _Float16* __restrict__ wdt, const float* __restrict__ bd,
    const float* __restrict__ xp, const _Float16* __restrict__ wpt, const float* __restrict__ bp,
    const int* __restrict__ ei, unsigned* __restrict__ bhist, __half* __restrict__ xbuf) {
    __shared__ unsigned lh[256];
    int bid = blockIdx.x;
    if (bid < NB_PROJD) {
        proj_direct<F_DRUG>(xd, wdt, bd, xbuf, N_DRUG, 0, bid);
    } else if (bid < NB_PROJD + NB_PROJP) {
        proj_direct<F_PROT>(xp, wpt, bp, xbuf, N_PROT, N_DRUG, bid - NB_PROJD);
    } else {
        int blk = bid - NB_PROJD - NB_PROJP;
        int t = threadIdx.x;
        lh[t] = 0;
        __syncthreads();
        int eb = blk * CH, ee = min(NE, eb + CH);
        for (int e = eb + t; e < ee; e += 256)
            atomicAdd(&lh[((unsigned)ei[NE + e]) >> 8], 1u);
        __syncthreads();
        bhist[(size_t)t * NBK1 + blk] = lh[t];
    }
}

// ---------------- scan step A: per-bucket row sums ----------------
__global__ __launch_bounds__(256) void kA(const unsigned* __restrict__ bhist,
                                          unsigned* __restrict__ rsum) {
    __shared__ unsigned s[256];
    int j = blockIdx.x, t = threadIdx.x;
    s[t] = bhist[(size_t)j * NBK1 + t];
    __syncthreads();
    for (int off = 128; off; off >>= 1) {
        if (t < off) s[t] += s[t + off];
        __syncthreads();
    }
    if (t == 0) rsum[j] = s[0];
}

// ---------------- scan step B: exclusive scan of bucket totals ----------------
__global__ __launch_bounds__(256) void kB(const unsigned* __restrict__ rsum,
                                          unsigned* __restrict__ rbase) {
    __shared__ unsigned s[256];
    int t = threadIdx.x;
    unsigned c = rsum[t];
    s[t] = c;
    __syncthreads();
    for (int off = 1; off < 256; off <<= 1) {
        unsigned v = s[t]; unsigned u = (t >= off) ? s[t - off] : 0;
        __syncthreads(); s[t] = v + u; __syncthreads();
    }
    rbase[t] = s[t] - c;
    if (t == 255) rbase[256] = s[255];
}

// ---------------- scan step C: per-bucket row exclusive scan + offset ----------------
__global__ __launch_bounds__(256) void kC(unsigned* __restrict__ bhist,
                                          const unsigned* __restrict__ rbase) {
    __shared__ unsigned s[256];
    int j = blockIdx.x, t = threadIdx.x;
    unsigned c = bhist[(size_t)j * NBK1 + t];
    s[t] = c;
    __syncthreads();
    for (int off = 1; off < 256; off <<= 1) {
        unsigned v = s[t]; unsigned u = (t >= off) ? s[t - off] : 0;
        __syncthreads(); s[t] = v + u; __syncthreads();
    }
    bhist[(size_t)j * NBK1 + t] = rbase[j] + s[t] - c;
}

// ---------------- bucket partition-scatter, XCD-contiguous chunk remap ----------------
// Consecutive chunks (whose tmp runs share cache lines) are handled by blocks on
// the same XCD (bid%8 groups), eliminating cross-XCD dirty-line sharing.
__global__ __launch_bounds__(256) void k_part(
    const int* __restrict__ ei, const unsigned* __restrict__ base,
    unsigned* __restrict__ tmp) {
    __shared__ unsigned lcur[256];
    int bid = blockIdx.x;
    int c = ((bid & 7) << 5) | (bid >> 3);   // XCD-contiguous chunk id
    int t = threadIdx.x;
    lcur[t] = base[(size_t)t * NBK1 + c];
    __syncthreads();
    int eb = c * CH, ee = min(NE, eb + CH);
    for (int e = eb + t; e < ee; e += 256) {
        unsigned s = (unsigned)ei[e];
        unsigned d = (unsigned)ei[NE + e];
        unsigned pos = atomicAdd(&lcur[d >> 8], 1u);
        tmp[pos] = ((d & 255u) << 16) | s;
    }
}

// ---------------- fused: per-bucket CSR finalize || conv layer 0 ----------------
__global__ __launch_bounds__(256) void k_csrconv(
    const unsigned* __restrict__ tmp, const unsigned* __restrict__ rbase,
    int* __restrict__ rp, float* __restrict__ dis, unsigned short* __restrict__ csr,
    const __half* __restrict__ xbuf, const _Float16* __restrict__ cwt,
    __half* __restrict__ xwh) {
    __shared__ unsigned lbin[256], lofs[256], lcur[256];
    int bid = blockIdx.x;
    if (bid >= NB_BKT) {
        conv_direct(xbuf, cwt, xwh, bid - NB_BKT);
        return;
    }
    int b = bid, t = threadIdx.x;
    unsigned nb0 = rbase[b], nb1 = rbase[b + 1];
    lbin[t] = 0;
    __syncthreads();
    for (unsigned i = nb0 + t; i < nb1; i += 256)
        atomicAdd(&lbin[tmp[i] >> 16], 1u);
    __syncthreads();
    unsigned c = lbin[t];
    lofs[t] = c;
    __syncthreads();
    for (int off = 1; off < 256; off <<= 1) {
        unsigned v = lofs[t]; unsigned u = (t >= off) ? lofs[t - off] : 0;
        __syncthreads(); lofs[t] = v + u; __syncthreads();
    }
    unsigned r = nb0 + lofs[t] - c;
    int node = b * 256 + t;
    if (node < NN) {
        rp[node] = (int)r;
        dis[node] = rsqrtf((float)c + 1.0f);
    }
    lcur[t] = r;
    __syncthreads();
    for (unsigned i = nb0 + t; i < nb1; i += 256) {
        unsigned rec = tmp[i];
        unsigned pos = atomicAdd(&lcur[rec >> 16], 1u);
        csr[pos] = (unsigned short)(rec & 0xffffu);
    }
    if (b == 0 && t == 0) rp[NN] = NE;
}

// ---------------- standalone conv (layers 1,2) ----------------
__global__ __launch_bounds__(256) void k_conv(
    const __half* __restrict__ X, const _Float16* __restrict__ Wt, __half* __restrict__ out) {
    conv_direct(X, Wt, out, blockIdx.x);
}

// ---------------- SpMM quarter-wave, 8-deep gather pipeline ----------------
// FIRST: build pack[] = src | f16(dis_s*dis_d)<<16 from csr+dis while aggregating.
// lane: q = lane>>4 (edge slot), g = lane&15 (features 4g..4g+3).
template <bool FIRST, bool LAST>
__global__ __launch_bounds__(256) void k_spmm(
    const int* __restrict__ rp, const unsigned short* __restrict__ csr,
    unsigned* __restrict__ pack, const float* __restrict__ dis,
    const __half* __restrict__ xw,
    const float* __restrict__ bias, __half* __restrict__ xout,
    const float* __restrict__ lw, const float* __restrict__ lb,
    float* __restrict__ y) {
    int lane = threadIdx.x & 63;
    int d = blockIdx.x * 4 + (threadIdx.x >> 6);
    if (d >= NN) return;
    int q = lane >> 4, g = lane & 15;
    int beg = rp[d], end = rp[d + 1];
    float dd = dis[d];
    const _Float16* xh = (const _Float16*)xw;
    float ax = 0.f, ay = 0.f, az = 0.f, aw = 0.f;

    int n = end - beg; if (n > 64) n = 64;
    unsigned rv = 0;
    if (lane < n) {
        if (FIRST) {
            int s = csr[beg + lane];
            float w0 = dis[s] * dd;
            rv = (unsigned)s | ((unsigned)__half_as_ushort(__float2half(w0)) << 16);
            pack[beg + lane] = rv;
        } else rv = pack[beg + lane];
    }
    for (int b0 = beg; b0 < end; ) {
        int nb = b0 + 64;
        int n2 = end - nb; if (n2 > 64) n2 = 64;
        unsigned rv2 = 0;
        if (n2 > 0 && lane < n2) {
            if (FIRST) {
                int s = csr[nb + lane];
                float w0 = dis[s] * dd;
                rv2 = (unsigned)s | ((unsigned)__half_as_ushort(__float2half(w0)) << 16);
                pack[nb + lane] = rv2;
            } else rv2 = pack[nb + lane];
        }
        int nsteps = (n + 3) >> 2;
        for (int j0 = 0; j0 < nsteps; j0 += 8) {
            int m = nsteps - j0; if (m > 8) m = 8;
            h4 xv[8]; float wv[8];
            #pragma unroll
            for (int k = 0; k < 8; ++k) {
                if (k < m) {
                    unsigned r = __shfl(rv, (j0 + k) * 4 + q);   // r==0 masks idx>=n
                    wv[k] = __half2float(__ushort_as_half((unsigned short)(r >> 16)));
                    xv[k] = *(const h4*)&xh[((r & 0xffffu) << 6) + (g << 2)];
                }
            }
            #pragma unroll
            for (int k = 0; k < 8; ++k) {
                if (k < m) {
                    ax += wv[k] * (float)xv[k][0];
                    ay += wv[k] * (float)xv[k][1];
                    az += wv[k] * (float)xv[k][2];
                    aw += wv[k] * (float)xv[k][3];
                }
            }
        }
        b0 = nb; n = n2; rv = rv2;
    }
    // reduce across the 4 quarters
    ax += __shfl_xor(ax, 16); ay += __shfl_xor(ay, 16);
    az += __shfl_xor(az, 16); aw += __shfl_xor(aw, 16);
    ax += __shfl_xor(ax, 32); ay += __shfl_xor(ay, 32);
    az += __shfl_xor(az, 32); aw += __shfl_xor(aw, 32);

    // epilogue: self term + bias + relu (edge weights pre-multiplied)
    float sn = dd * dd;
    h4 xs = *(const h4*)&xh[((unsigned)d << 6) + (g << 2)];
    float4 bv = *(const float4*)&bias[g << 2];
    float vx = fmaxf(ax + sn * (float)xs[0] + bv.x, 0.f);
    float vy = fmaxf(ay + sn * (float)xs[1] + bv.y, 0.f);
    float vz = fmaxf(az + sn * (float)xs[2] + bv.z, 0.f);
    float vw = fmaxf(aw + sn * (float)xs[3] + bv.w, 0.f);
    if (LAST) {
        float4 lv = *(const float4*)&lw[g << 2];
        float t = vx * lv.x + vy * lv.y + vz * lv.z + vw * lv.w;
        #pragma unroll
        for (int off = 8; off; off >>= 1) t += __shfl_xor(t, off);
        if (lane == 0) y[d] = t + lb[0];
    } else if (q == 0) {
        h4 hv;
        hv[0] = (_Float16)vx; hv[1] = (_Float16)vy;
        hv[2] = (_Float16)vz; hv[3] = (_Float16)vw;
        *(h4*)((_Float16*)xout + ((size_t)d << 6) + (g << 2)) = hv;
    }
}

// ---------------- edge scoring: sigmoid(y[src]*y[dst]) ----------------
__global__ void k_out(const float* __restrict__ y, const int* __restrict__ ls,
                      const int* __restrict__ ld, float* __restrict__ out) {
    int e = blockIdx.x * blockDim.x + threadIdx.x;
    if (e < NL) {
        float z = y[ls[e]] * y[ld[e]];
        out[e] = 1.f / (1.f + __expf(-z));
    }
}

static inline size_t up256(size_t x) { return (x + 255) & ~(size_t)255; }

extern "C" void kernel_launch(void* const* d_in, const int* in_sizes, int n_in,
                              void* d_out, int out_size, void* d_ws, size_t ws_size,
                              hipStream_t stream) {
    const float* x_drug = (const float*)d_in[0];
    const float* x_prot = (const float*)d_in[1];
    const float* W_drug = (const float*)d_in[2];
    const float* b_drug = (const float*)d_in[3];
    const float* W_prot = (const float*)d_in[4];
    const float* b_prot = (const float*)d_in[5];
    const float* conv_W = (const float*)d_in[6];
    const float* conv_b = (const float*)d_in[7];
    const float* lin_W  = (const float*)d_in[8];
    const float* lin_b  = (const float*)d_in[9];
    const int*   ei     = (const int*)d_in[10];
    const int*   lsrc   = (const int*)d_in[11];
    const int*   ldst   = (const int*)d_in[12];
    float* out = (float*)d_out;

    char* w = (char*)d_ws;
    size_t off = 0;
    unsigned* bhist = (unsigned*)(w + off); off = up256(off + (size_t)256 * NBK1 * 4);
    unsigned* rsum  = (unsigned*)(w + off); off = up256(off + 256 * 4);
    unsigned* rbase = (unsigned*)(w + off); off = up256(off + 257 * 4);
    unsigned* tmp   = (unsigned*)(w + off); off = up256(off + (size_t)NE * 4);
    unsigned short* csr = (unsigned short*)(w + off); off = up256(off + (size_t)NE * 2);
    unsigned* pack  = (unsigned*)(w + off); off = up256(off + (size_t)NE * 4);
    int*    rp   = (int*)(w + off);    off = up256(off + (size_t)(NN + 1) * 4);
    float*  dis  = (float*)(w + off);  off = up256(off + (size_t)NN * 4);
    __half* xbuf = (__half*)(w + off); off = up256(off + (size_t)NN * H * 2);
    __half* xwh  = (__half*)(w + off); off = up256(off + (size_t)NN * H * 2);
    float*  y    = (float*)(w + off);  off = up256(off + (size_t)NN * 4);
    _Float16* wdt = (_Float16*)(w + off); off = up256(off + (size_t)64 * F_DRUG * 2);
    _Float16* wpt = (_Float16*)(w + off); off = up256(off + (size_t)64 * F_PROT * 2);
    _Float16* cwt = (_Float16*)(w + off); off = up256(off + (size_t)3 * 64 * 64 * 2);

    k_wprep<<<64, 256, 0, stream>>>(W_drug, W_prot, conv_W, wdt, wpt, cwt);

    // proj_drug || proj_prot || coarse hist
    k_front<<<NB_PROJD + NB_PROJP + NBK1, 256, 0, stream>>>(
        x_drug, wdt, b_drug, x_prot, wpt, b_prot, ei, bhist, xbuf);

    kA<<<256, 256, 0, stream>>>(bhist, rsum);
    kB<<<1, 256, 0, stream>>>(rsum, rbase);
    kC<<<256, 256, 0, stream>>>(bhist, rbase);

    // bucket partition-scatter (XCD-contiguous chunks)
    k_part<<<NBK1, 256, 0, stream>>>(ei, bhist, tmp);

    // per-bucket CSR finalize || conv layer 0
    k_csrconv<<<NB_BKT + NB_CONV, 256, 0, stream>>>(
        tmp, rbase, rp, dis, csr, xbuf, cwt, xwh);

    // layer 0 (builds pack on the fly)
    k_spmm<true, false><<<NB_ROW4, 256, 0, stream>>>(
        rp, csr, pack, dis, xwh, conv_b, xbuf, nullptr, nullptr, nullptr);
    // layer 1
    k_conv<<<NB_CONV, 256, 0, stream>>>(xbuf, cwt + 4096, xwh);
    k_spmm<false, false><<<NB_ROW4, 256, 0, stream>>>(
        rp, csr, pack, dis, xwh, conv_b + H, xbuf, nullptr, nullptr, nullptr);
    // layer 2 (fused y epilogue)
    k_conv<<<NB_CONV, 256, 0, stream>>>(xbuf, cwt + 8192, xwh);
    k_spmm<false, true><<<NB_ROW4, 256, 0, stream>>>(
        rp, csr, pack, dis, xwh, conv_b + 2 * H, nullptr, lin_W, lin_b, y);

    k_out<<<(NL + 255) / 256, 256, 0, stream>>>(y, lsrc, ldst, out);
}